// Round 5
// baseline (680.909 us; speedup 1.0000x reference)
//
#include <hip/hip_runtime.h>
#include <hip/hip_fp16.h>

#define C_    15
#define H_    256
#define O_    512
#define T_    60
#define B_    1024
#define G3H_  768
#define TS    16
#define MAXG  12
#define NSLOT 96
#define NPROD 96
#define NU    80          // packed 16-col units per camera: 48 gh + 32 out
#define PACKB 300         // pack blocks (4 cu each)
#define CVTB  2880        // cvt blocks (256 float4 each)
#define TCH   10          // t-steps per consumer chunk / publish cadence

typedef __attribute__((ext_vector_type(8))) short bf16x8;
typedef __attribute__((ext_vector_type(4))) float f32x4;

__device__ __forceinline__ unsigned short f2bf(float f) {
    union { float f; unsigned u; } v; v.f = f;
    return (unsigned short)((v.u + 0x7FFFu + ((v.u >> 16) & 1u)) >> 16);   // RTNE
}
__device__ __forceinline__ float sigf(float x) { return 1.f / (1.f + __expf(-x)); }

// ---------------- prep: sort+flags (block 0) + pack (1..PACKB) + cvt (rest) ----------------
__global__ __launch_bounds__(256) void prep_kernel(
    const int* __restrict__ cam, const float* __restrict__ Wih,
    const float* __restrict__ Whh, const float* __restrict__ Wc,
    int* __restrict__ order, int* __restrict__ tcam, int* __restrict__ toff,
    int* __restrict__ tcnt, int* __restrict__ flags,
    unsigned short* __restrict__ Wih_b, unsigned short* __restrict__ Wpack)
{
    int bid = blockIdx.x, tid = threadIdx.x;
    if (bid == 0) {
        __shared__ int cnt[C_], start[C_], fill[C_];
        if (tid < C_) cnt[tid] = 0;
        if (tid < NSLOT) { tcam[tid] = -1; toff[tid] = 0; tcnt[tid] = 0; flags[tid] = 0; }
        __syncthreads();
        for (int b = tid; b < B_; b += 256) atomicAdd(&cnt[cam[b]], 1);
        __syncthreads();
        if (tid == 0) {
            int run = 0;
            for (int c = 0; c < C_; ++c) { start[c] = run; fill[c] = run; run += cnt[c]; }
        }
        __syncthreads();
        for (int b = tid; b < B_; b += 256) {
            int pos = atomicAdd(&fill[cam[b]], 1);
            order[pos] = b;
        }
        __syncthreads();
        if (tid == 0) {
            int gcnt[8] = {0,0,0,0,0,0,0,0};
            for (int c = 0; c < C_; ++c) gcnt[c & 7] += (cnt[c] + TS - 1) / TS;
            int maxg = 0;
            for (int g = 0; g < 8; ++g) maxg = max(maxg, gcnt[g]);
            if (maxg <= MAXG) {
                // camera c tiles land on slots ≡ (c&7) mod 8 -> stable XCD -> weights L2-resident
                for (int g = 0; g < 8; ++g) {
                    int k = 0;
                    for (int c = g; c < C_; c += 8)
                        for (int r = 0; r < cnt[c]; r += TS) {
                            int slot = g + 8 * k;
                            tcam[slot] = c; toff[slot] = start[c] + r;
                            tcnt[slot] = min(TS, cnt[c] - r); ++k;
                        }
                }
            } else {
                int ti = 0;
                for (int c = 0; c < C_; ++c)
                    for (int r = 0; r < cnt[c]; r += TS) {
                        tcam[ti] = c; toff[ti] = start[c] + r;
                        tcnt[ti] = min(TS, cnt[c] - r); ++ti;
                    }
            }
        }
    } else if (bid <= PACKB) {
        // pack Whh|Wc -> bf16 in exact B-fragment order (4 cu per block)
        int cu = (bid - 1) * 4 + (tid >> 6);       // c*NU + u
        int c = cu / NU, u = cu - c * NU;
        int lane = tid & 63, q = lane >> 4, l16 = lane & 15;
        const float* src = (u < 48)
            ? &Whh[((size_t)c * G3H_ + u * 16 + l16) * H_]
            : &Wc[((size_t)c * O_ + (u - 48) * 16 + l16) * H_];
        unsigned short* dst = Wpack + ((size_t)cu * 8) * 512 + lane * 8;
#pragma unroll
        for (int kk = 0; kk < 8; ++kk) {
            float4 v0 = *(const float4*)&src[kk * 32 + q * 8];
            float4 v1 = *(const float4*)&src[kk * 32 + q * 8 + 4];
            unsigned short* d = dst + kk * 512;
            d[0] = f2bf(v0.x); d[1] = f2bf(v0.y); d[2] = f2bf(v0.z); d[3] = f2bf(v0.w);
            d[4] = f2bf(v1.x); d[5] = f2bf(v1.y); d[6] = f2bf(v1.z); d[7] = f2bf(v1.w);
        }
    } else {
        // cvt: Wih fp32 -> bf16 row-major
        int i = (bid - 1 - PACKB) * 256 + tid;     // < C_*G3H_*H_/4 exactly
        float4 v = ((const float4*)Wih)[i];
        unsigned p0 = (unsigned)f2bf(v.x) | ((unsigned)f2bf(v.y) << 16);
        unsigned p1 = (unsigned)f2bf(v.z) | ((unsigned)f2bf(v.w) << 16);
        ((uint2*)Wih_b)[i] = make_uint2(p0, p1);
    }
}

// ---------------- mega: producers (recurrence, blocks 0..95) + consumers (out GEMM, 96..191) ----
// Producer slot s publishes flags[s]=t+1 every TCH steps (threadfence + agent release store).
// Consumer slot s spin-waits per chunk; deadlock-free: consumers only wait on producers.
__global__ __launch_bounds__(512, 1) void mega_kernel(
    const float* __restrict__ x, const unsigned short* __restrict__ Wih_b,
    const unsigned short* __restrict__ Wpack, const float* __restrict__ bih,
    const float* __restrict__ bhh, const float* __restrict__ bc,
    const int* __restrict__ order, const int* __restrict__ tcam,
    const int* __restrict__ toff, const int* __restrict__ tcnt,
    int* __restrict__ flags, unsigned short* __restrict__ htraj,
    unsigned short* __restrict__ outT, int direct, float* __restrict__ outp)
{
    int bid = blockIdx.x, tid = threadIdx.x;
    int w = tid >> 6, lane = tid & 63, q = lane >> 4, l16 = lane & 15;

    if (bid < NPROD) {
        // ======================= PRODUCER (r3 persist + gi prologue) =======================
        int slot = bid;
        int c = tcam[slot]; if (c < 0) return;
        int cnt = tcnt[slot], off = toff[slot];

        __shared__ float gisT[G3H_][20];             // gi in fragment layout (61.4 KB)
        __shared__ unsigned short hbf[2][16][264];   // double-buffered bf16 h (16.9 KB)

        // --- stage x -> hbf[0] as bf16 (zero-padded rows) ---
        for (int idx = tid; idx < TS * 64; idx += 512) {
            int m = idx >> 6, c4 = idx & 63;
            float4 v = make_float4(0.f, 0.f, 0.f, 0.f);
            if (m < cnt) v = *(const float4*)&x[(size_t)order[off + m] * H_ + (c4 << 2)];
            unsigned p0 = (unsigned)f2bf(v.x) | ((unsigned)f2bf(v.y) << 16);
            unsigned p1 = (unsigned)f2bf(v.z) | ((unsigned)f2bf(v.w) << 16);
            *(uint2*)&hbf[0][m][c4 << 2] = make_uint2(p0, p1);
        }
        __syncthreads();

        // --- gi prologue: 6 16-col units per wave, gi = x*Wih^T + bih + bhh(r,z) -> gisT ---
        {
            f32x4 acc[6];
#pragma unroll
            for (int ui = 0; ui < 6; ++ui) acc[ui] = (f32x4){0.f, 0.f, 0.f, 0.f};
#pragma unroll
            for (int kk = 0; kk < 8; ++kk) {
                bf16x8 a = *(const bf16x8*)&hbf[0][l16][kk * 32 + q * 8];
#pragma unroll
                for (int ui = 0; ui < 6; ++ui) {
                    int col = (w * 6 + ui) * 16 + l16;
                    bf16x8 b = *(const bf16x8*)(Wih_b + ((size_t)c * G3H_ + col) * H_ + kk * 32 + q * 8);
                    acc[ui] = __builtin_amdgcn_mfma_f32_16x16x32_bf16(a, b, acc[ui], 0, 0, 0);
                }
            }
#pragma unroll
            for (int ui = 0; ui < 6; ++ui) {
                int col = (w * 6 + ui) * 16 + l16;
                float bias = bih[c * G3H_ + col] + (col < 2 * H_ ? bhh[c * G3H_ + col] : 0.f);
#pragma unroll
                for (int r = 0; r < 4; ++r) gisT[col][q * 4 + r] = acc[ui][r] + bias;
            }
        }
        __builtin_amdgcn_sched_barrier(0);

        // --- gh weights -> registers: wf[0..1]=r wf[2..3]=z wf[4..5]=n ---
        bf16x8 wf[6][8];
#pragma unroll
        for (int ii = 0; ii < 3; ++ii)
#pragma unroll
            for (int jj = 0; jj < 2; ++jj)
#pragma unroll
                for (int kk = 0; kk < 8; ++kk)
                    wf[ii * 2 + jj][kk] = *(const bf16x8*)(
                        Wpack + (((size_t)(c * NU + ii * 16 + w + 8 * jj)) * 8 + kk) * 512 + lane * 8);

        float bhn[2], hreg[2][4];
#pragma unroll
        for (int i = 0; i < 2; ++i) {
            int col = (w + 8 * i) * 16 + l16;
            bhn[i] = bhh[c * G3H_ + 2 * H_ + col];
#pragma unroll
            for (int r = 0; r < 4; ++r) hreg[i][r] = 0.f;
        }
        unsigned short* hp = htraj + ((size_t)slot * TS + q * 4) * 256 + w * 16 + l16;
        __syncthreads();

#pragma unroll 2
        for (int s = 0; s < T_; ++s) {
            int wbuf = s & 1, rbuf = wbuf ^ 1;
            f32x4 acc[6];
#pragma unroll
            for (int ui = 0; ui < 6; ++ui) acc[ui] = (f32x4){0.f, 0.f, 0.f, 0.f};
            if (s > 0) {
#pragma unroll
                for (int kk = 0; kk < 8; ++kk) {
                    bf16x8 a = *(const bf16x8*)&hbf[rbuf][l16][kk * 32 + q * 8];
#pragma unroll
                    for (int ui = 0; ui < 6; ++ui)
                        acc[ui] = __builtin_amdgcn_mfma_f32_16x16x32_bf16(a, wf[ui][kk], acc[ui], 0, 0, 0);
                }
            }
#pragma unroll
            for (int i = 0; i < 2; ++i) {
                int col = (w + 8 * i) * 16 + l16;
                f32x4 gr = *(const f32x4*)&gisT[col][q * 4];
                f32x4 gz = *(const f32x4*)&gisT[H_ + col][q * 4];
                f32x4 gn = *(const f32x4*)&gisT[2 * H_ + col][q * 4];
#pragma unroll
                for (int r = 0; r < 4; ++r) {
                    float rr = sigf(gr[r] + acc[i][r]);
                    float zz = sigf(gz[r] + acc[2 + i][r]);
                    float pre = gn[r] + rr * (acc[4 + i][r] + bhn[i]);
                    float nn = 2.f * sigf(2.f * pre) - 1.f;          // tanh
                    float hn = (1.f - zz) * nn + zz * hreg[i][r];
                    hreg[i][r] = hn;
                    unsigned short hb = f2bf(hn);
                    hbf[wbuf][q * 4 + r][col] = hb;
                    hp[r * 256 + i * 128] = hb;
                }
            }
            hp += (size_t)NSLOT * TS * 256;
            if (((s + 1) % TCH) == 0) {
                // publish: make htraj[.. s] visible device-wide, then release the flag
                __threadfence();
                __syncthreads();
                if (tid == 0)
                    __hip_atomic_store(&flags[slot], s + 1, __ATOMIC_RELEASE,
                                       __HIP_MEMORY_SCOPE_AGENT);
            } else {
                asm volatile("s_waitcnt lgkmcnt(0)" ::: "memory");  // ds ops visible; stores fly on
                __builtin_amdgcn_s_barrier();
                __builtin_amdgcn_sched_barrier(0);
            }
        }
    } else {
        // ======================= CONSUMER (r3 out_kernel, chunk-gated) =======================
        int slot = bid - NPROD;
        int c = tcam[slot]; if (c < 0) return;
        int n = tcnt[slot], off = toff[slot];
        __shared__ unsigned short hb[2][16][264];
        __shared__ int ord16[16];
        if (tid < 16) ord16[tid] = (tid < n) ? order[off + tid] : -1;

        bf16x8 wfo[4][8];
        const unsigned short* wb = Wpack + ((size_t)c * NU + 48 + w * 4) * 8 * 512 + lane * 8;
#pragma unroll
        for (int ui = 0; ui < 4; ++ui)
#pragma unroll
            for (int kk = 0; kk < 8; ++kk)
                wfo[ui][kk] = *(const bf16x8*)(wb + ((size_t)ui * 8 + kk) * 512);
        float bcr[4];
#pragma unroll
        for (int ui = 0; ui < 4; ++ui)
            bcr[ui] = bc[c * O_ + (w * 4 + ui) * 16 + l16];

        int m = tid >> 5, c8 = (tid & 31) * 8;
        for (int tz = 0; tz < T_ / TCH; ++tz) {
            if (tid == 0) {
                while (__hip_atomic_load(&flags[slot], __ATOMIC_ACQUIRE,
                                         __HIP_MEMORY_SCOPE_AGENT) < (tz + 1) * TCH)
                    __builtin_amdgcn_s_sleep(8);
            }
            __syncthreads();                       // gate + ord16/hb reuse safety

            const unsigned short* hsrc =
                &htraj[(((size_t)(tz * TCH) * NSLOT + slot) * 16 + m) * 256 + c8];
            uint4 stg = *(const uint4*)hsrc;       // tile t0 of chunk
            *(uint4*)&hb[0][m][c8] = stg;
            asm volatile("s_waitcnt lgkmcnt(0)" ::: "memory");
            __builtin_amdgcn_s_barrier();
            __builtin_amdgcn_sched_barrier(0);

            for (int ti = 0; ti < TCH; ++ti) {
                int t = tz * TCH + ti;
                int cur = ti & 1;
                if (ti + 1 < TCH)                  // issue next tile load early
                    stg = *(const uint4*)(hsrc + (size_t)(ti + 1) * NSLOT * TS * 256);
                f32x4 acc[4];
#pragma unroll
                for (int ui = 0; ui < 4; ++ui) acc[ui] = (f32x4){0.f, 0.f, 0.f, 0.f};
#pragma unroll
                for (int kk = 0; kk < 8; ++kk) {
                    bf16x8 a = *(const bf16x8*)&hb[cur][l16][kk * 32 + q * 8];
#pragma unroll
                    for (int ui = 0; ui < 4; ++ui)
                        acc[ui] = __builtin_amdgcn_mfma_f32_16x16x32_bf16(a, wfo[ui][kk], acc[ui], 0, 0, 0);
                }
#pragma unroll
                for (int ui = 0; ui < 4; ++ui) {
                    int o = (w * 4 + ui) * 16 + l16;
#pragma unroll
                    for (int r = 0; r < 4; ++r) {
                        int b = ord16[q * 4 + r];
                        if (b >= 0) {
                            float val = sigf(acc[ui][r] + bcr[ui]);
                            if (direct) outp[((size_t)b * O_ + o) * T_ + t] = val;
                            else outT[((size_t)t * B_ + b) * O_ + o] =
                                     __half_as_ushort(__float2half_rn(val));
                        }
                    }
                }
                if (ti + 1 < TCH) {
                    *(uint4*)&hb[cur ^ 1][m][c8] = stg;
                    asm volatile("s_waitcnt lgkmcnt(0)" ::: "memory");
                    __builtin_amdgcn_s_barrier();
                    __builtin_amdgcn_sched_barrier(0);
                }
            }
        }
    }
}

// ---------------- transpose [T][B][O] fp16 -> [B][O][T] fp32 ----------------
__global__ __launch_bounds__(256) void transpose_kernel(
    const unsigned short* __restrict__ outT, float* __restrict__ outp)
{
    int b = blockIdx.x, o0 = blockIdx.y * 64;
    __shared__ float ts[T_][65];
    int tid = threadIdx.x;
    for (int idx = tid; idx < T_ * 64; idx += 256) {
        int t = idx >> 6, o = idx & 63;
        ts[t][o] = __half2float(__ushort_as_half(outT[((size_t)t * B_ + b) * O_ + o0 + o]));
    }
    __syncthreads();
    for (int idx = tid; idx < 64 * T_; idx += 256) {
        int o = idx / T_, t = idx - o * T_;
        outp[((size_t)b * O_ + o0 + o) * T_ + t] = ts[t][o];
    }
}

extern "C" void kernel_launch(void* const* d_in, const int* in_sizes, int n_in,
                              void* d_out, int out_size, void* d_ws, size_t ws_size,
                              hipStream_t stream)
{
    const float* x   = (const float*)d_in[0];
    const int*   cam = (const int*)d_in[1];
    const float* Wih = (const float*)d_in[2];
    const float* Whh = (const float*)d_in[3];
    const float* bih = (const float*)d_in[4];
    const float* bhh = (const float*)d_in[5];
    const float* Wc  = (const float*)d_in[6];
    const float* bc  = (const float*)d_in[7];
    float* outp = (float*)d_out;

    char* w = (char*)d_ws;
    unsigned short* Wih_b = (unsigned short*)w; w += (size_t)C_ * G3H_ * H_ * 2;
    unsigned short* Wpack = (unsigned short*)w; w += (size_t)C_ * NU * 8 * 512 * 2;
    int* order = (int*)w; w += B_ * 4;
    int* tcam  = (int*)w; w += NSLOT * 4;
    int* toff  = (int*)w; w += NSLOT * 4;
    int* tcnt  = (int*)w; w += NSLOT * 4;
    int* flags = (int*)w; w += NSLOT * 4;
    unsigned short* htraj = (unsigned short*)w; w += (size_t)T_ * NSLOT * 16 * 256 * 2;
    unsigned short* outT = (unsigned short*)w;
    size_t need = (size_t)(w - (char*)d_ws) + (size_t)T_ * B_ * O_ * 2;
    int direct = (ws_size < need) ? 1 : 0;

    prep_kernel<<<1 + PACKB + CVTB, 256, 0, stream>>>(cam, Wih, Whh, Wc, order, tcam,
                                                      toff, tcnt, flags, Wih_b, Wpack);
    mega_kernel<<<NPROD + NSLOT, 512, 0, stream>>>(x, Wih_b, Wpack, bih, bhh, bc, order,
                                                   tcam, toff, tcnt, flags, htraj, outT,
                                                   direct, outp);
    if (!direct)
        transpose_kernel<<<dim3(B_, O_ / 64), 256, 0, stream>>>(outT, outp);
}

// Round 6
// 434.079 us; speedup vs baseline: 1.5686x; 1.5686x over previous
//
#include <hip/hip_runtime.h>
#include <hip/hip_fp16.h>

#define C_    15
#define H_    256
#define O_    512
#define T_    60
#define B_    1024
#define G3H_  768
#define TS    16
#define MAXG  12
#define NSLOT 96
#define NU    80          // packed 16-col units per camera: 48 gh + 32 out
#define PACKB 300         // pack blocks (4 cu each)
#define CVTB  2880        // cvt blocks (256 float4 each)

typedef __attribute__((ext_vector_type(8))) short bf16x8;
typedef __attribute__((ext_vector_type(4))) float f32x4;

__device__ __forceinline__ unsigned short f2bf(float f) {
    union { float f; unsigned u; } v; v.f = f;
    return (unsigned short)((v.u + 0x7FFFu + ((v.u >> 16) & 1u)) >> 16);   // RTNE
}
__device__ __forceinline__ float sigf(float x) { return 1.f / (1.f + __expf(-x)); }

// ---------------- prep: sort (block 0) + pack (1..PACKB) + cvt (rest), one launch ----------------
__global__ __launch_bounds__(256) void prep_kernel(
    const int* __restrict__ cam, const float* __restrict__ Wih,
    const float* __restrict__ Whh, const float* __restrict__ Wc,
    int* __restrict__ order, int* __restrict__ tcam, int* __restrict__ toff,
    int* __restrict__ tcnt, unsigned short* __restrict__ Wih_b,
    unsigned short* __restrict__ Wpack)
{
    int bid = blockIdx.x, tid = threadIdx.x;
    if (bid == 0) {
        __shared__ int cnt[C_], start[C_], fill[C_];
        if (tid < C_) cnt[tid] = 0;
        if (tid < NSLOT) { tcam[tid] = -1; toff[tid] = 0; tcnt[tid] = 0; }
        __syncthreads();
        for (int b = tid; b < B_; b += 256) atomicAdd(&cnt[cam[b]], 1);
        __syncthreads();
        if (tid == 0) {
            int run = 0;
            for (int c = 0; c < C_; ++c) { start[c] = run; fill[c] = run; run += cnt[c]; }
        }
        __syncthreads();
        for (int b = tid; b < B_; b += 256) {
            int pos = atomicAdd(&fill[cam[b]], 1);
            order[pos] = b;
        }
        __syncthreads();
        if (tid == 0) {
            int gcnt[8] = {0,0,0,0,0,0,0,0};
            for (int c = 0; c < C_; ++c) gcnt[c & 7] += (cnt[c] + TS - 1) / TS;
            int maxg = 0;
            for (int g = 0; g < 8; ++g) maxg = max(maxg, gcnt[g]);
            if (maxg <= MAXG) {
                // camera c tiles land on slots ≡ (c&7) mod 8 -> stable XCD -> weights L2-resident
                for (int g = 0; g < 8; ++g) {
                    int k = 0;
                    for (int c = g; c < C_; c += 8)
                        for (int r = 0; r < cnt[c]; r += TS) {
                            int slot = g + 8 * k;
                            tcam[slot] = c; toff[slot] = start[c] + r;
                            tcnt[slot] = min(TS, cnt[c] - r); ++k;
                        }
                }
            } else {
                int ti = 0;
                for (int c = 0; c < C_; ++c)
                    for (int r = 0; r < cnt[c]; r += TS) {
                        tcam[ti] = c; toff[ti] = start[c] + r;
                        tcnt[ti] = min(TS, cnt[c] - r); ++ti;
                    }
            }
        }
    } else if (bid <= PACKB) {
        // pack Whh|Wc -> bf16 in exact B-fragment order (4 cu per block)
        int cu = (bid - 1) * 4 + (tid >> 6);       // c*NU + u
        int c = cu / NU, u = cu - c * NU;
        int lane = tid & 63, q = lane >> 4, l16 = lane & 15;
        const float* src = (u < 48)
            ? &Whh[((size_t)c * G3H_ + u * 16 + l16) * H_]
            : &Wc[((size_t)c * O_ + (u - 48) * 16 + l16) * H_];
        unsigned short* dst = Wpack + ((size_t)cu * 8) * 512 + lane * 8;
#pragma unroll
        for (int kk = 0; kk < 8; ++kk) {
            float4 v0 = *(const float4*)&src[kk * 32 + q * 8];
            float4 v1 = *(const float4*)&src[kk * 32 + q * 8 + 4];
            unsigned short* d = dst + kk * 512;
            d[0] = f2bf(v0.x); d[1] = f2bf(v0.y); d[2] = f2bf(v0.z); d[3] = f2bf(v0.w);
            d[4] = f2bf(v1.x); d[5] = f2bf(v1.y); d[6] = f2bf(v1.z); d[7] = f2bf(v1.w);
        }
    } else {
        // cvt: Wih fp32 -> bf16 row-major
        int i = (bid - 1 - PACKB) * 256 + tid;     // < C_*G3H_*H_/4 exactly
        float4 v = ((const float4*)Wih)[i];
        unsigned p0 = (unsigned)f2bf(v.x) | ((unsigned)f2bf(v.y) << 16);
        unsigned p1 = (unsigned)f2bf(v.z) | ((unsigned)f2bf(v.w) << 16);
        ((uint2*)Wih_b)[i] = make_uint2(p0, p1);
    }
}

// ---------------- persistent recurrence, gi GEMM fused as prologue (r3 body verbatim) ----------------
// Prologue (proven r5): stage x->hbf[0], gi = x*Wih^T + bih + bhh(r,z) -> gisT in fragment
// layout. Loop = r3's proven 153.5us body: 8 waves, wf[6][8] weight regs, per-step LDS gi
// reads, raw lgkmcnt-only barrier so htraj stores stay in flight.
__global__ __launch_bounds__(512, 2) void persist_kernel(
    const float* __restrict__ x, const unsigned short* __restrict__ Wih_b,
    const unsigned short* __restrict__ Wpack, const float* __restrict__ bih,
    const float* __restrict__ bhh, const int* __restrict__ order,
    const int* __restrict__ tcam, const int* __restrict__ toff,
    const int* __restrict__ tcnt, unsigned short* __restrict__ htraj)
{
    int slot = blockIdx.x;
    int c = tcam[slot]; if (c < 0) return;
    int cnt = tcnt[slot], off = toff[slot];
    int tid = threadIdx.x, w = tid >> 6, lane = tid & 63, q = lane >> 4, l16 = lane & 15;

    __shared__ float gisT[G3H_][20];             // gi in fragment layout (61.4 KB)
    __shared__ unsigned short hbf[2][16][264];   // double-buffered bf16 h (16.9 KB)

    // --- stage x -> hbf[0] as bf16 (zero-padded rows) ---
    for (int idx = tid; idx < TS * 64; idx += 512) {
        int m = idx >> 6, c4 = idx & 63;
        float4 v = make_float4(0.f, 0.f, 0.f, 0.f);
        if (m < cnt) v = *(const float4*)&x[(size_t)order[off + m] * H_ + (c4 << 2)];
        unsigned p0 = (unsigned)f2bf(v.x) | ((unsigned)f2bf(v.y) << 16);
        unsigned p1 = (unsigned)f2bf(v.z) | ((unsigned)f2bf(v.w) << 16);
        *(uint2*)&hbf[0][m][c4 << 2] = make_uint2(p0, p1);
    }
    __syncthreads();

    // --- gi prologue: 6 16-col units per wave -> gisT (proven r5 producer path) ---
    {
        f32x4 acc[6];
#pragma unroll
        for (int ui = 0; ui < 6; ++ui) acc[ui] = (f32x4){0.f, 0.f, 0.f, 0.f};
#pragma unroll
        for (int kk = 0; kk < 8; ++kk) {
            bf16x8 a = *(const bf16x8*)&hbf[0][l16][kk * 32 + q * 8];
#pragma unroll
            for (int ui = 0; ui < 6; ++ui) {
                int col = (w * 6 + ui) * 16 + l16;
                bf16x8 b = *(const bf16x8*)(Wih_b + ((size_t)c * G3H_ + col) * H_ + kk * 32 + q * 8);
                acc[ui] = __builtin_amdgcn_mfma_f32_16x16x32_bf16(a, b, acc[ui], 0, 0, 0);
            }
        }
#pragma unroll
        for (int ui = 0; ui < 6; ++ui) {
            int col = (w * 6 + ui) * 16 + l16;
            float bias = bih[c * G3H_ + col] + (col < 2 * H_ ? bhh[c * G3H_ + col] : 0.f);
#pragma unroll
            for (int r = 0; r < 4; ++r) gisT[col][q * 4 + r] = acc[ui][r] + bias;
        }
    }
    __builtin_amdgcn_sched_barrier(0);

    // --- gh weights -> registers once: wf[0..1]=r wf[2..3]=z wf[4..5]=n ---
    bf16x8 wf[6][8];
#pragma unroll
    for (int ii = 0; ii < 3; ++ii)
#pragma unroll
        for (int jj = 0; jj < 2; ++jj)
#pragma unroll
            for (int kk = 0; kk < 8; ++kk)
                wf[ii * 2 + jj][kk] = *(const bf16x8*)(
                    Wpack + (((size_t)(c * NU + ii * 16 + w + 8 * jj)) * 8 + kk) * 512 + lane * 8);

    float bhn[2], hreg[2][4];
#pragma unroll
    for (int i = 0; i < 2; ++i) {
        int col = (w + 8 * i) * 16 + l16;
        bhn[i] = bhh[c * G3H_ + 2 * H_ + col];
#pragma unroll
        for (int r = 0; r < 4; ++r) hreg[i][r] = 0.f;
    }
    unsigned short* hp = htraj + ((size_t)slot * TS + q * 4) * 256 + w * 16 + l16;
    __syncthreads();   // gisT visible; all waves done reading hbf[0] (x) before s=0 overwrites it

#pragma unroll 2
    for (int s = 0; s < T_; ++s) {
        int wbuf = s & 1, rbuf = wbuf ^ 1;
        f32x4 acc[6];
#pragma unroll
        for (int ui = 0; ui < 6; ++ui) acc[ui] = (f32x4){0.f, 0.f, 0.f, 0.f};
        if (s > 0) {
#pragma unroll
            for (int kk = 0; kk < 8; ++kk) {
                bf16x8 a = *(const bf16x8*)&hbf[rbuf][l16][kk * 32 + q * 8];
#pragma unroll
                for (int ui = 0; ui < 6; ++ui)
                    acc[ui] = __builtin_amdgcn_mfma_f32_16x16x32_bf16(a, wf[ui][kk], acc[ui], 0, 0, 0);
            }
        }
#pragma unroll
        for (int i = 0; i < 2; ++i) {
            int col = (w + 8 * i) * 16 + l16;
            f32x4 gr = *(const f32x4*)&gisT[col][q * 4];
            f32x4 gz = *(const f32x4*)&gisT[H_ + col][q * 4];
            f32x4 gn = *(const f32x4*)&gisT[2 * H_ + col][q * 4];
#pragma unroll
            for (int r = 0; r < 4; ++r) {
                float rr = sigf(gr[r] + acc[i][r]);
                float zz = sigf(gz[r] + acc[2 + i][r]);
                float pre = gn[r] + rr * (acc[4 + i][r] + bhn[i]);
                float nn = 2.f * sigf(2.f * pre) - 1.f;          // tanh
                float hn = (1.f - zz) * nn + zz * hreg[i][r];
                hreg[i][r] = hn;
                unsigned short hb = f2bf(hn);
                hbf[wbuf][q * 4 + r][col] = hb;
                hp[r * 256 + i * 128] = hb;
            }
        }
        hp += (size_t)NSLOT * TS * 256;
        asm volatile("s_waitcnt lgkmcnt(0)" ::: "memory");   // ds ops visible; htraj stores keep flying
        __builtin_amdgcn_s_barrier();
        __builtin_amdgcn_sched_barrier(0);                   // no hoisting of next ds_read above barrier
    }
}

// ---------------- out GEMM over trajectory, direct [B][O][T] fp32 writes (proven r4) ----------------
__global__ __launch_bounds__(512, 2) void out_kernel(
    const unsigned short* __restrict__ Wpack, const float* __restrict__ bc,
    const unsigned short* __restrict__ htraj, const int* __restrict__ order,
    const int* __restrict__ tcam, const int* __restrict__ toff,
    const int* __restrict__ tcnt, float* __restrict__ outp)
{
    int slot = blockIdx.x;
    int c = tcam[slot]; if (c < 0) return;
    int n = tcnt[slot], off = toff[slot];
    int tz = blockIdx.z;
    int tid = threadIdx.x, w = tid >> 6, lane = tid & 63, q = lane >> 4, l16 = lane & 15;
    __shared__ unsigned short hb[2][16][264];
    __shared__ int ord16[16];
    if (tid < 16) ord16[tid] = (tid < n) ? order[off + tid] : -1;

    int u = blockIdx.y * 8 + w;                    // out unit 0..31
    bf16x8 wf[8];
    const unsigned short* wb = Wpack + ((size_t)c * NU + 48 + u) * 8 * 512 + lane * 8;
#pragma unroll
    for (int kk = 0; kk < 8; ++kk) wf[kk] = *(const bf16x8*)(wb + (size_t)kk * 512);
    float bcr = bc[c * O_ + u * 16 + l16];

    int m = tid >> 5, c8 = (tid & 31) * 8;
    const unsigned short* hsrc =
        &htraj[(((size_t)(tz * 10) * NSLOT + slot) * 16 + m) * 256 + c8];
    uint4 stg = *(const uint4*)hsrc;               // tile t0
    *(uint4*)&hb[0][m][c8] = stg;
    __syncthreads();                               // ord16 + hb[0] visible

    float vals[4][10];
#pragma unroll
    for (int ti = 0; ti < 10; ++ti) {
        int cur = ti & 1;
        if (ti + 1 < 10)                           // issue next tile load early
            stg = *(const uint4*)(hsrc + (size_t)(ti + 1) * NSLOT * TS * 256);
        f32x4 acc = (f32x4){0.f, 0.f, 0.f, 0.f};
#pragma unroll
        for (int kk = 0; kk < 8; ++kk) {
            bf16x8 a = *(const bf16x8*)&hb[cur][l16][kk * 32 + q * 8];
            acc = __builtin_amdgcn_mfma_f32_16x16x32_bf16(a, wf[kk], acc, 0, 0, 0);
        }
#pragma unroll
        for (int r = 0; r < 4; ++r) vals[r][ti] = sigf(acc[r] + bcr);
        if (ti + 1 < 10) {
            *(uint4*)&hb[cur ^ 1][m][c8] = stg;    // compiler waits vmcnt for stg only
            asm volatile("s_waitcnt lgkmcnt(0)" ::: "memory");
            __builtin_amdgcn_s_barrier();
            __builtin_amdgcn_sched_barrier(0);
        }
    }
    int o = u * 16 + l16;
#pragma unroll
    for (int r = 0; r < 4; ++r) {
        int b = ord16[q * 4 + r];
        if (b >= 0) {
            float* dst = &outp[((size_t)b * O_ + o) * T_ + tz * 10];
#pragma unroll
            for (int j = 0; j < 5; ++j)
                *(float2*)&dst[j * 2] = make_float2(vals[r][2 * j], vals[r][2 * j + 1]);
        }
    }
}

extern "C" void kernel_launch(void* const* d_in, const int* in_sizes, int n_in,
                              void* d_out, int out_size, void* d_ws, size_t ws_size,
                              hipStream_t stream)
{
    const float* x   = (const float*)d_in[0];
    const int*   cam = (const int*)d_in[1];
    const float* Wih = (const float*)d_in[2];
    const float* Whh = (const float*)d_in[3];
    const float* bih = (const float*)d_in[4];
    const float* bhh = (const float*)d_in[5];
    const float* Wc  = (const float*)d_in[6];
    const float* bc  = (const float*)d_in[7];
    float* outp = (float*)d_out;

    char* w = (char*)d_ws;
    unsigned short* Wih_b = (unsigned short*)w; w += (size_t)C_ * G3H_ * H_ * 2;
    unsigned short* Wpack = (unsigned short*)w; w += (size_t)C_ * NU * 8 * 512 * 2;
    int* order = (int*)w; w += B_ * 4;
    int* tcam  = (int*)w; w += NSLOT * 4;
    int* toff  = (int*)w; w += NSLOT * 4;
    int* tcnt  = (int*)w; w += NSLOT * 4;
    unsigned short* htraj = (unsigned short*)w;

    prep_kernel<<<1 + PACKB + CVTB, 256, 0, stream>>>(cam, Wih, Whh, Wc, order, tcam,
                                                      toff, tcnt, Wih_b, Wpack);
    persist_kernel<<<NSLOT, 512, 0, stream>>>(x, Wih_b, Wpack, bih, bhh, order, tcam,
                                              toff, tcnt, htraj);
    out_kernel<<<dim3(NSLOT, 4, 6), 512, 0, stream>>>(Wpack, bc, htraj, order, tcam,
                                                      toff, tcnt, outp);
}